// Round 1
// baseline (381.582 us; speedup 1.0000x reference)
//
#include <hip/hip_runtime.h>
#include <hip/hip_bf16.h>

// Problem constants
#define S_LEN 2048
#define DMODEL 2048
#define NH 16
#define HDIM 128
#define SCALE_F 0.08838834764831845f  // 1/sqrt(128)

typedef __attribute__((ext_vector_type(8))) short bf16x8;  // 8 bf16 = 4 VGPRs
typedef __attribute__((ext_vector_type(4))) float f32x4;

__device__ __forceinline__ unsigned short f2bf(float f) {
  unsigned int u = __float_as_uint(f);
  u += 0x7FFFu + ((u >> 16) & 1u);   // round-to-nearest-even
  return (unsigned short)(u >> 16);
}

__device__ __forceinline__ void gload16(const void* g, void* l) {
  __builtin_amdgcn_global_load_lds(
      (const __attribute__((address_space(1))) unsigned int*)g,
      (__attribute__((address_space(3))) unsigned int*)l, 16, 0, 0);
}

// ---------------- fp32 -> bf16 conversion ----------------
__global__ __launch_bounds__(256) void cvt_f32_bf16(
    const float* __restrict__ in, unsigned short* __restrict__ out, int n4) {
  int i = blockIdx.x * blockDim.x + threadIdx.x;
  if (i < n4) {
    const float4 v = *(const float4*)(in + i * 4);
    ushort4 o;
    o.x = f2bf(v.x); o.y = f2bf(v.y); o.z = f2bf(v.z); o.w = f2bf(v.w);
    *(ushort4*)(out + i * 4) = o;
  }
}

// ---------------- QKV projection GEMM ----------------
// C[m][n] = sum_k A[m][k] * W[n][k] + bias[n], m in [0,4096), n in [0,6144)
// n<2048 -> Q [B,H,S,HD]; n<4096 -> K [B,H,S,HD]; else V^T [B,H,HD,S]
__global__ __launch_bounds__(256, 2) void gemm_qkv(
    const unsigned short* __restrict__ A,    // [4096][2048] bf16
    const unsigned short* __restrict__ W,    // [6144][2048] bf16
    const float* __restrict__ qbias, const float* __restrict__ kbias,
    const float* __restrict__ vbias,
    unsigned short* __restrict__ qo, unsigned short* __restrict__ ko,
    unsigned short* __restrict__ vto) {
  __shared__ unsigned short As[128 * 32];  // 8 KB
  __shared__ unsigned short Bs[128 * 32];
  const int t = threadIdx.x;
  const int lane = t & 63;
  const int w = t >> 6;
  const int m0 = blockIdx.x * 128;
  const int n0 = blockIdx.y * 128;
  const int wr = w >> 1, wc = w & 1;

  f32x4 acc[4][4];
#pragma unroll
  for (int i = 0; i < 4; i++)
#pragma unroll
    for (int j = 0; j < 4; j++)
#pragma unroll
      for (int e = 0; e < 4; e++) acc[i][j][e] = 0.f;

  // staging: chunk c (16B) covers tile row c>>2, cols ((c&3)*8 .. +8)
  const int r0 = t >> 2;
  const int kc0 = (t & 3) * 8;
  const unsigned short* Arow0 = A + (m0 + r0) * DMODEL + kc0;
  const unsigned short* Arow1 = A + (m0 + 64 + r0) * DMODEL + kc0;
  const unsigned short* Wrow0 = W + (n0 + r0) * DMODEL + kc0;
  const unsigned short* Wrow1 = W + (n0 + 64 + r0) * DMODEL + kc0;
  char* AsB = (char*)As;
  char* BsB = (char*)Bs;

  const int frow = lane & 15;
  const int fcol = (lane >> 4) * 8;

  for (int k0 = 0; k0 < DMODEL; k0 += 32) {
    __syncthreads();
    gload16(Arow0 + k0, AsB + w * 1024);
    gload16(Arow1 + k0, AsB + 4096 + w * 1024);
    gload16(Wrow0 + k0, BsB + w * 1024);
    gload16(Wrow1 + k0, BsB + 4096 + w * 1024);
    __syncthreads();
    bf16x8 af[4], bfr[4];
#pragma unroll
    for (int i = 0; i < 4; i++)
      af[i] = *(const bf16x8*)&As[(wr * 64 + i * 16 + frow) * 32 + fcol];
#pragma unroll
    for (int j = 0; j < 4; j++)
      bfr[j] = *(const bf16x8*)&Bs[(wc * 64 + j * 16 + frow) * 32 + fcol];
#pragma unroll
    for (int i = 0; i < 4; i++)
#pragma unroll
      for (int j = 0; j < 4; j++)
        acc[i][j] = __builtin_amdgcn_mfma_f32_16x16x32_bf16(af[i], bfr[j],
                                                            acc[i][j], 0, 0, 0);
  }

  // epilogue: C row = m0+wr*64+i*16+(lane>>4)*4+reg, col = n0+wc*64+j*16+(lane&15)
  const int b_ = m0 >> 11;
  const int proj = n0 >> 11;  // uniform per block (2048 % 128 == 0)
  const int nn_base = (n0 & 2047) + wc * 64;
  const float* bias = (proj == 0) ? qbias : ((proj == 1) ? kbias : vbias);
#pragma unroll
  for (int j = 0; j < 4; j++) {
    const int nn = nn_base + j * 16 + (lane & 15);
    const int h = nn >> 7, hd = nn & 127;
    const float bv = bias[nn];
#pragma unroll
    for (int i = 0; i < 4; i++) {
      const int mrow = m0 + wr * 64 + i * 16 + (lane >> 4) * 4;
      const int s = mrow & 2047;
      if (proj == 2) {
        // V^T: [(b*NH+h)*HDIM + hd][S], 4 consecutive s -> one 8B store
        unsigned short* dst = vto + ((b_ * NH + h) * HDIM + hd) * S_LEN + s;
        ushort4 pk;
        pk.x = f2bf(acc[i][j][0] + bv);
        pk.y = f2bf(acc[i][j][1] + bv);
        pk.z = f2bf(acc[i][j][2] + bv);
        pk.w = f2bf(acc[i][j][3] + bv);
        *(ushort4*)dst = pk;
      } else {
        unsigned short* dst =
            ((proj == 0) ? qo : ko) + ((b_ * NH + h) * S_LEN + s) * HDIM + hd;
#pragma unroll
        for (int r = 0; r < 4; r++) dst[r * HDIM] = f2bf(acc[i][j][r] + bv);
      }
    }
  }
}

// ---------------- causal flash attention ----------------
// grid: x = q-tile (32), y = b*H (32). 4 waves x 16 q-rows, KV tiles of 64.
__global__ __launch_bounds__(256, 2) void attn_fwd(
    const unsigned short* __restrict__ Q,   // [B*H][S][128]
    const unsigned short* __restrict__ K,   // [B*H][S][128]
    const unsigned short* __restrict__ VT,  // [B*H][128][S]
    unsigned short* __restrict__ ctx) {     // [B][S][2048]
  __shared__ unsigned short Ks[64 * 128];   // 16 KB, row-swizzled (16B chunks)
  __shared__ unsigned short Vs[128 * 64];   // 16 KB, V^T tile, swizzled
  __shared__ unsigned short Ps[4][16 * 64]; // 8 KB, per-wave P, swizzled
  const int t = threadIdx.x, lane = t & 63, w = t >> 6;
  const int qt = blockIdx.x;
  const int bh = blockIdx.y;
  const unsigned short* Qb = Q + bh * (S_LEN * HDIM);
  const unsigned short* Kb = K + bh * (S_LEN * HDIM);
  const unsigned short* Vb = VT + bh * (HDIM * S_LEN);
  const int q0 = qt * 64 + w * 16;

  // Q fragments in registers: A-operand row = lane&15, k = dk*32 + 8*(lane>>4)
  bf16x8 qf[4];
  {
    const unsigned short* qrow = Qb + (q0 + (lane & 15)) * HDIM + (lane >> 4) * 8;
#pragma unroll
    for (int dk = 0; dk < 4; dk++) qf[dk] = *(const bf16x8*)(qrow + dk * 32);
  }

  float mrow[4], lrow[4];
  f32x4 oacc[8];
#pragma unroll
  for (int r = 0; r < 4; r++) { mrow[r] = -__builtin_inff(); lrow[r] = 0.f; }
#pragma unroll
  for (int d = 0; d < 8; d++)
#pragma unroll
    for (int e = 0; e < 4; e++) oacc[d][e] = 0.f;

  for (int kt = 0; kt <= qt; ++kt) {
    const int kv0 = kt * 64;
    __syncthreads();
    // stage K tile [64][128]: row = 256B = 16 chunks; source chunk ^= row&7
#pragma unroll
    for (int u = 0; u < 4; ++u) {
      const int c = t + u * 256;
      const int row = c >> 4, cc = c & 15;
      gload16(Kb + (kv0 + row) * HDIM + ((cc ^ (row & 7)) * 8),
              (char*)Ks + u * 4096 + w * 1024);
    }
    // stage V^T tile [128][64]: row = 128B = 8 chunks
#pragma unroll
    for (int u = 0; u < 4; ++u) {
      const int c = t + u * 256;
      const int row = c >> 3, cc = c & 7;
      gload16(Vb + row * S_LEN + kv0 + ((cc ^ (row & 7)) * 8),
              (char*)Vs + u * 4096 + w * 1024);
    }
    __syncthreads();

    // S = Q K^T  (16 q-rows x 64 kv-cols)
    f32x4 sacc[4];
#pragma unroll
    for (int ck = 0; ck < 4; ck++)
#pragma unroll
      for (int e = 0; e < 4; e++) sacc[ck][e] = 0.f;
#pragma unroll
    for (int ck = 0; ck < 4; ++ck) {
      const int krow = ck * 16 + (lane & 15);
#pragma unroll
      for (int dk = 0; dk < 4; ++dk) {
        const int chunk = dk * 4 + (lane >> 4);
        const bf16x8 kf = *(const bf16x8*)((const char*)Ks + krow * 256 +
                                           ((chunk ^ (krow & 7)) << 4));
        sacc[ck] = __builtin_amdgcn_mfma_f32_16x16x32_bf16(qf[dk], kf, sacc[ck],
                                                           0, 0, 0);
      }
    }
    // scale + causal mask (diagonal tile only)
#pragma unroll
    for (int ck = 0; ck < 4; ck++)
#pragma unroll
      for (int r = 0; r < 4; r++) sacc[ck][r] *= SCALE_F;
    if (kt == qt) {
#pragma unroll
      for (int ck = 0; ck < 4; ck++) {
        const int col = kv0 + ck * 16 + (lane & 15);
#pragma unroll
        for (int r = 0; r < 4; r++) {
          const int rowq = q0 + (lane >> 4) * 4 + r;
          if (col > rowq) sacc[ck][r] = -__builtin_inff();
        }
      }
    }
    // online softmax: row r lives in 16 lanes (cols), reg r
    float tmax[4];
#pragma unroll
    for (int r = 0; r < 4; r++)
      tmax[r] = fmaxf(fmaxf(sacc[0][r], sacc[1][r]),
                      fmaxf(sacc[2][r], sacc[3][r]));
#pragma unroll
    for (int off = 1; off < 16; off <<= 1)
#pragma unroll
      for (int r = 0; r < 4; r++)
        tmax[r] = fmaxf(tmax[r], __shfl_xor(tmax[r], off, 64));
    float corr[4];
#pragma unroll
    for (int r = 0; r < 4; r++) {
      const float mn = fmaxf(mrow[r], tmax[r]);
      corr[r] = __expf(mrow[r] - mn);  // 0 on first tile
      mrow[r] = mn;
    }
    float rsum[4] = {0.f, 0.f, 0.f, 0.f};
#pragma unroll
    for (int ck = 0; ck < 4; ck++)
#pragma unroll
      for (int r = 0; r < 4; r++) {
        const float p = __expf(sacc[ck][r] - mrow[r]);  // masked -> exp(-inf)=0
        rsum[r] += p;
        const int prow = (lane >> 4) * 4 + r;
        const int pcol = ck * 16 + (lane & 15);
        *(unsigned short*)((char*)Ps[w] +
                           ((prow * 128 + pcol * 2) ^ ((prow & 7) << 4))) =
            f2bf(p);
      }
#pragma unroll
    for (int off = 1; off < 16; off <<= 1)
#pragma unroll
      for (int r = 0; r < 4; r++) rsum[r] += __shfl_xor(rsum[r], off, 64);
#pragma unroll
    for (int r = 0; r < 4; r++) lrow[r] = lrow[r] * corr[r] + rsum[r];
#pragma unroll
    for (int d = 0; d < 8; d++)
#pragma unroll
      for (int r = 0; r < 4; r++) oacc[d][r] *= corr[r];

    // O += P V : A = P [16 q][64 k], B = V [64 k][128 d] (from V^T tile)
    bf16x8 pf[2];
    {
      const int prow = lane & 15;
#pragma unroll
      for (int kk = 0; kk < 2; kk++) {
        const int chunk = kk * 4 + (lane >> 4);
        pf[kk] = *(const bf16x8*)((const char*)Ps[w] + prow * 128 +
                                  ((chunk ^ (prow & 7)) << 4));
      }
    }
#pragma unroll
    for (int d = 0; d < 8; ++d) {
      const int vrow = d * 16 + (lane & 15);
#pragma unroll
      for (int kk = 0; kk < 2; ++kk) {
        const int chunk = kk * 4 + (lane >> 4);
        const bf16x8 vf = *(const bf16x8*)((const char*)Vs + vrow * 128 +
                                           ((chunk ^ (vrow & 7)) << 4));
        oacc[d] = __builtin_amdgcn_mfma_f32_16x16x32_bf16(pf[kk], vf, oacc[d],
                                                          0, 0, 0);
      }
    }
  }

  // epilogue: ctx[b][s][h*128 + d]
  const int b_ = bh >> 4, h = bh & 15;
#pragma unroll
  for (int r = 0; r < 4; r++) {
    const float inv = 1.f / lrow[r];
    const int srow = q0 + (lane >> 4) * 4 + r;
    unsigned short* dst = ctx + (b_ * S_LEN + srow) * DMODEL + h * HDIM + (lane & 15);
#pragma unroll
    for (int d = 0; d < 8; d++) dst[d * 16] = f2bf(oacc[d][r] * inv);
  }
}

// ---------------- output projection GEMM ----------------
__global__ __launch_bounds__(256, 2) void gemm_out(
    const unsigned short* __restrict__ A,  // ctx [4096][2048] bf16
    const unsigned short* __restrict__ W,  // o_w [2048][2048] bf16
    const float* __restrict__ bias, float* __restrict__ out) {
  __shared__ unsigned short As[128 * 32];
  __shared__ unsigned short Bs[128 * 32];
  const int t = threadIdx.x;
  const int lane = t & 63;
  const int w = t >> 6;
  const int m0 = blockIdx.x * 128;
  const int n0 = blockIdx.y * 128;
  const int wr = w >> 1, wc = w & 1;

  f32x4 acc[4][4];
#pragma unroll
  for (int i = 0; i < 4; i++)
#pragma unroll
    for (int j = 0; j < 4; j++)
#pragma unroll
      for (int e = 0; e < 4; e++) acc[i][j][e] = 0.f;

  const int r0 = t >> 2;
  const int kc0 = (t & 3) * 8;
  const unsigned short* Arow0 = A + (m0 + r0) * DMODEL + kc0;
  const unsigned short* Arow1 = A + (m0 + 64 + r0) * DMODEL + kc0;
  const unsigned short* Wrow0 = W + (n0 + r0) * DMODEL + kc0;
  const unsigned short* Wrow1 = W + (n0 + 64 + r0) * DMODEL + kc0;
  char* AsB = (char*)As;
  char* BsB = (char*)Bs;
  const int frow = lane & 15;
  const int fcol = (lane >> 4) * 8;

  for (int k0 = 0; k0 < DMODEL; k0 += 32) {
    __syncthreads();
    gload16(Arow0 + k0, AsB + w * 1024);
    gload16(Arow1 + k0, AsB + 4096 + w * 1024);
    gload16(Wrow0 + k0, BsB + w * 1024);
    gload16(Wrow1 + k0, BsB + 4096 + w * 1024);
    __syncthreads();
    bf16x8 af[4], bfr[4];
#pragma unroll
    for (int i = 0; i < 4; i++)
      af[i] = *(const bf16x8*)&As[(wr * 64 + i * 16 + frow) * 32 + fcol];
#pragma unroll
    for (int j = 0; j < 4; j++)
      bfr[j] = *(const bf16x8*)&Bs[(wc * 64 + j * 16 + frow) * 32 + fcol];
#pragma unroll
    for (int i = 0; i < 4; i++)
#pragma unroll
      for (int j = 0; j < 4; j++)
        acc[i][j] = __builtin_amdgcn_mfma_f32_16x16x32_bf16(af[i], bfr[j],
                                                            acc[i][j], 0, 0, 0);
  }

#pragma unroll
  for (int j = 0; j < 4; j++) {
    const int n = n0 + wc * 64 + j * 16 + (lane & 15);
    const float bv = bias[n];
#pragma unroll
    for (int i = 0; i < 4; i++) {
      const int mrow = m0 + wr * 64 + i * 16 + (lane >> 4) * 4;
      float* dst = out + mrow * DMODEL + n;
#pragma unroll
      for (int r = 0; r < 4; r++) dst[r * DMODEL] = acc[i][j][r] + bv;
    }
  }
}

// ---------------- host launcher ----------------
extern "C" void kernel_launch(void* const* d_in, const int* in_sizes, int n_in,
                              void* d_out, int out_size, void* d_ws,
                              size_t ws_size, hipStream_t stream) {
  const float* x  = (const float*)d_in[0];
  const float* qw = (const float*)d_in[1];
  const float* qb = (const float*)d_in[2];
  const float* kw = (const float*)d_in[3];
  const float* kb = (const float*)d_in[4];
  const float* vw = (const float*)d_in[5];
  const float* vb = (const float*)d_in[6];
  const float* ow = (const float*)d_in[7];
  const float* ob = (const float*)d_in[8];
  float* out = (float*)d_out;

  // workspace layout (bf16 elements); total 117,440,512 bytes
  unsigned short* xb   = (unsigned short*)d_ws;        // x      [4096][2048]
  unsigned short* wqkv = xb + (size_t)8388608;         // [6144][2048]
  unsigned short* wo   = wqkv + (size_t)12582912;      // [2048][2048]
  unsigned short* qt_  = wo + (size_t)4194304;         // Q  [B,H,S,HD]
  unsigned short* kt_  = qt_ + (size_t)8388608;        // K  [B,H,S,HD]
  unsigned short* vt_  = kt_ + (size_t)8388608;        // V^T[B,H,HD,S]
  unsigned short* ctx  = vt_ + (size_t)8388608;        // ctx[B,S,D]

  cvt_f32_bf16<<<8192, 256, 0, stream>>>(x, xb, 2097152);
  cvt_f32_bf16<<<4096, 256, 0, stream>>>(qw, wqkv, 1048576);
  cvt_f32_bf16<<<4096, 256, 0, stream>>>(kw, wqkv + 4194304, 1048576);
  cvt_f32_bf16<<<4096, 256, 0, stream>>>(vw, wqkv + 8388608, 1048576);
  cvt_f32_bf16<<<4096, 256, 0, stream>>>(ow, wo, 1048576);

  gemm_qkv<<<dim3(32, 48), 256, 0, stream>>>(xb, wqkv, qb, kb, vb, qt_, kt_, vt_);
  attn_fwd<<<dim3(32, 32), 256, 0, stream>>>(qt_, kt_, vt_, ctx);
  gemm_out<<<dim3(32, 16), 256, 0, stream>>>(ctx, wo, ob, out);
}

// Round 2
// 293.213 us; speedup vs baseline: 1.3014x; 1.3014x over previous
//
#include <hip/hip_runtime.h>
#include <hip/hip_bf16.h>

// Problem constants
#define S_LEN 2048
#define DMODEL 2048
#define NH 16
#define HDIM 128
#define SCALE_F 0.08838834764831845f  // 1/sqrt(128)

typedef __attribute__((ext_vector_type(8))) short bf16x8;  // 8 bf16 = 4 VGPRs
typedef __attribute__((ext_vector_type(4))) float f32x4;

__device__ __forceinline__ unsigned short f2bf(float f) {
  unsigned int u = __float_as_uint(f);
  u += 0x7FFFu + ((u >> 16) & 1u);   // round-to-nearest-even
  return (unsigned short)(u >> 16);
}

__device__ __forceinline__ void gload16(const void* g, void* l) {
  __builtin_amdgcn_global_load_lds(
      (const __attribute__((address_space(1))) unsigned int*)g,
      (__attribute__((address_space(3))) unsigned int*)l, 16, 0, 0);
}

// ---------------- fp32 -> bf16 conversion ----------------
__global__ __launch_bounds__(256) void cvt_f32_bf16(
    const float* __restrict__ in, unsigned short* __restrict__ out, int n4) {
  int i = blockIdx.x * blockDim.x + threadIdx.x;
  if (i < n4) {
    const float4 v = *(const float4*)(in + i * 4);
    ushort4 o;
    o.x = f2bf(v.x); o.y = f2bf(v.y); o.z = f2bf(v.z); o.w = f2bf(v.w);
    *(ushort4*)(out + i * 4) = o;
  }
}

// ---------------- QKV projection GEMM ----------------
// C[m][n] = sum_k A[m][k] * W[n][k] + bias[n], m in [0,4096), n in [0,6144)
// n<2048 -> Q [B,H,S,HD]; n<4096 -> K [B,H,S,HD]; else V^T [B,H,HD,S]
__global__ __launch_bounds__(256, 2) void gemm_qkv(
    const unsigned short* __restrict__ A,    // [4096][2048] bf16
    const unsigned short* __restrict__ W,    // [6144][2048] bf16
    const float* __restrict__ qbias, const float* __restrict__ kbias,
    const float* __restrict__ vbias,
    unsigned short* __restrict__ qo, unsigned short* __restrict__ ko,
    unsigned short* __restrict__ vto) {
  __shared__ unsigned short As[128 * 32];  // 8 KB
  __shared__ unsigned short Bs[128 * 32];
  const int t = threadIdx.x;
  const int lane = t & 63;
  const int w = t >> 6;
  const int m0 = blockIdx.x * 128;
  const int n0 = blockIdx.y * 128;
  const int wr = w >> 1, wc = w & 1;

  f32x4 acc[4][4];
#pragma unroll
  for (int i = 0; i < 4; i++)
#pragma unroll
    for (int j = 0; j < 4; j++)
#pragma unroll
      for (int e = 0; e < 4; e++) acc[i][j][e] = 0.f;

  // staging: chunk c (16B) covers tile row c>>2, cols ((c&3)*8 .. +8)
  const int r0 = t >> 2;
  const int kc0 = (t & 3) * 8;
  const unsigned short* Arow0 = A + (m0 + r0) * DMODEL + kc0;
  const unsigned short* Arow1 = A + (m0 + 64 + r0) * DMODEL + kc0;
  const unsigned short* Wrow0 = W + (n0 + r0) * DMODEL + kc0;
  const unsigned short* Wrow1 = W + (n0 + 64 + r0) * DMODEL + kc0;
  char* AsB = (char*)As;
  char* BsB = (char*)Bs;

  const int frow = lane & 15;
  const int fcol = (lane >> 4) * 8;

  for (int k0 = 0; k0 < DMODEL; k0 += 32) {
    __syncthreads();
    gload16(Arow0 + k0, AsB + w * 1024);
    gload16(Arow1 + k0, AsB + 4096 + w * 1024);
    gload16(Wrow0 + k0, BsB + w * 1024);
    gload16(Wrow1 + k0, BsB + 4096 + w * 1024);
    __syncthreads();
    bf16x8 af[4], bfr[4];
#pragma unroll
    for (int i = 0; i < 4; i++)
      af[i] = *(const bf16x8*)&As[(wr * 64 + i * 16 + frow) * 32 + fcol];
#pragma unroll
    for (int j = 0; j < 4; j++)
      bfr[j] = *(const bf16x8*)&Bs[(wc * 64 + j * 16 + frow) * 32 + fcol];
#pragma unroll
    for (int i = 0; i < 4; i++)
#pragma unroll
      for (int j = 0; j < 4; j++)
        acc[i][j] = __builtin_amdgcn_mfma_f32_16x16x32_bf16(af[i], bfr[j],
                                                            acc[i][j], 0, 0, 0);
  }

  // epilogue: C row = m0+wr*64+i*16+(lane>>4)*4+reg, col = n0+wc*64+j*16+(lane&15)
  const int b_ = m0 >> 11;
  const int proj = n0 >> 11;  // uniform per block (2048 % 128 == 0)
  const int nn_base = (n0 & 2047) + wc * 64;
  const float* bias = (proj == 0) ? qbias : ((proj == 1) ? kbias : vbias);
#pragma unroll
  for (int j = 0; j < 4; j++) {
    const int nn = nn_base + j * 16 + (lane & 15);
    const int h = nn >> 7, hd = nn & 127;
    const float bv = bias[nn];
#pragma unroll
    for (int i = 0; i < 4; i++) {
      const int mrow = m0 + wr * 64 + i * 16 + (lane >> 4) * 4;
      const int s = mrow & 2047;
      if (proj == 2) {
        // V^T: [(b*NH+h)*HDIM + hd][S], 4 consecutive s -> one 8B store
        unsigned short* dst = vto + ((b_ * NH + h) * HDIM + hd) * S_LEN + s;
        ushort4 pk;
        pk.x = f2bf(acc[i][j][0] + bv);
        pk.y = f2bf(acc[i][j][1] + bv);
        pk.z = f2bf(acc[i][j][2] + bv);
        pk.w = f2bf(acc[i][j][3] + bv);
        *(ushort4*)dst = pk;
      } else {
        unsigned short* dst =
            ((proj == 0) ? qo : ko) + ((b_ * NH + h) * S_LEN + s) * HDIM + hd;
#pragma unroll
        for (int r = 0; r < 4; r++) dst[r * HDIM] = f2bf(acc[i][j][r] + bv);
      }
    }
  }
}

// ---------------- causal flash attention ----------------
// grid: x = q-tile pair (16), y = b*H (32). Block handles q-tiles x and 31-x
// (uniform 33 KV-tile iterations per block -> no causal load-imbalance tail).
// 4 waves x 16 q-rows, KV tiles of 64, double-buffered K/V staging.
__global__ __launch_bounds__(256, 2) void attn_fwd(
    const unsigned short* __restrict__ Q,   // [B*H][S][128]
    const unsigned short* __restrict__ K,   // [B*H][S][128]
    const unsigned short* __restrict__ VT,  // [B*H][128][S]
    unsigned short* __restrict__ ctx) {     // [B][S][2048]
  __shared__ unsigned short Ks[2][64 * 128];   // 2x16 KB, row-swizzled 16B chunks
  __shared__ unsigned short Vs[2][128 * 64];   // 2x16 KB, V^T tile, swizzled
  __shared__ unsigned short Ps[4][16 * 64];    // 8 KB, per-wave P, swizzled
  const int t = threadIdx.x, lane = t & 63, w = t >> 6;
  const int bh = blockIdx.y;
  const unsigned short* Qb = Q + bh * (S_LEN * HDIM);
  const unsigned short* Kb = K + bh * (S_LEN * HDIM);
  const unsigned short* Vb = VT + bh * (HDIM * S_LEN);
  const int b_ = bh >> 4, h = bh & 15;

  // staging address components (same for every tile)
  const int krow_s = t >> 2;                    // K: 64 rows x 16 chunks
  const int kchunk = t & 3;                     // 4 chunks per thread row-slot? no:
  // K tile [64][128]: 1024 chunks of 16B; thread handles c = t + u*256.
  // V^T tile [128][64]: 1024 chunks of 16B; c = t + u*256.

  auto stageKV = [&](int buf, int kv0) {
#pragma unroll
    for (int u = 0; u < 4; ++u) {
      const int c = t + u * 256;
      const int row = c >> 4, cc = c & 15;
      gload16(Kb + (kv0 + row) * HDIM + ((cc ^ (row & 7)) * 8),
              (char*)Ks[buf] + u * 4096 + w * 1024);
    }
#pragma unroll
    for (int u = 0; u < 4; ++u) {
      const int c = t + u * 256;
      const int row = c >> 3, cc = c & 7;
      gload16(Vb + row * S_LEN + kv0 + ((cc ^ (row & 7)) * 8),
              (char*)Vs[buf] + u * 4096 + w * 1024);
    }
  };

#pragma unroll 1
  for (int pi = 0; pi < 2; ++pi) {
    const int qtile = pi ? (31 - blockIdx.x) : blockIdx.x;
    const int q0 = qtile * 64 + w * 16;

    // Q fragments: A-operand row = lane&15, k = dk*32 + 8*(lane>>4)
    bf16x8 qf[4];
    {
      const unsigned short* qrow =
          Qb + (q0 + (lane & 15)) * HDIM + (lane >> 4) * 8;
#pragma unroll
      for (int dk = 0; dk < 4; dk++) qf[dk] = *(const bf16x8*)(qrow + dk * 32);
    }

    float mrow[4], lrow[4];
    f32x4 oacc[8];
#pragma unroll
    for (int r = 0; r < 4; r++) { mrow[r] = -__builtin_inff(); lrow[r] = 0.f; }
#pragma unroll
    for (int d = 0; d < 8; d++)
#pragma unroll
      for (int e = 0; e < 4; e++) oacc[d][e] = 0.f;

    const int nt = qtile + 1;
    stageKV(0, 0);
    __syncthreads();  // drain prologue stage
    int cur = 0;

#pragma unroll 1
    for (int kt = 0; kt < nt; ++kt) {
      // issue next tile's loads first; they complete under this tile's compute
      if (kt + 1 < nt) stageKV(cur ^ 1, (kt + 1) * 64);

      const unsigned short* Kc = Ks[cur];
      const unsigned short* Vc = Vs[cur];
      const int kv0 = kt * 64;

      // S = Q K^T  (16 q-rows x 64 kv-cols)
      f32x4 sacc[4];
#pragma unroll
      for (int ck = 0; ck < 4; ck++)
#pragma unroll
        for (int e = 0; e < 4; e++) sacc[ck][e] = 0.f;
      __builtin_amdgcn_s_setprio(1);
#pragma unroll
      for (int ck = 0; ck < 4; ++ck) {
        const int krow = ck * 16 + (lane & 15);
#pragma unroll
        for (int dk = 0; dk < 4; ++dk) {
          const int chunk = dk * 4 + (lane >> 4);
          const bf16x8 kf = *(const bf16x8*)((const char*)Kc + krow * 256 +
                                             ((chunk ^ (krow & 7)) << 4));
          sacc[ck] = __builtin_amdgcn_mfma_f32_16x16x32_bf16(qf[dk], kf,
                                                             sacc[ck], 0, 0, 0);
        }
      }
      __builtin_amdgcn_s_setprio(0);
      // scale + causal mask (diagonal tile only)
#pragma unroll
      for (int ck = 0; ck < 4; ck++)
#pragma unroll
        for (int r = 0; r < 4; r++) sacc[ck][r] *= SCALE_F;
      if (kt == qtile) {
#pragma unroll
        for (int ck = 0; ck < 4; ck++) {
          const int col = kv0 + ck * 16 + (lane & 15);
#pragma unroll
          for (int r = 0; r < 4; r++) {
            const int rowq = q0 + (lane >> 4) * 4 + r;
            if (col > rowq) sacc[ck][r] = -__builtin_inff();
          }
        }
      }
      // online softmax: row r lives in 16 lanes (cols), reg r
      float tmax[4];
#pragma unroll
      for (int r = 0; r < 4; r++)
        tmax[r] = fmaxf(fmaxf(sacc[0][r], sacc[1][r]),
                        fmaxf(sacc[2][r], sacc[3][r]));
#pragma unroll
      for (int off = 1; off < 16; off <<= 1)
#pragma unroll
        for (int r = 0; r < 4; r++)
          tmax[r] = fmaxf(tmax[r], __shfl_xor(tmax[r], off, 64));
      // defer-max (T13): only rescale when max grew by > 8 (P bounded by e^8)
      bool need = false;
#pragma unroll
      for (int r = 0; r < 4; r++) need |= (tmax[r] > mrow[r] + 8.f);
      if (__any(need)) {
#pragma unroll
        for (int r = 0; r < 4; r++) {
          const float mn = fmaxf(mrow[r], tmax[r]);
          const float corr = __expf(mrow[r] - mn);  // 0 on first tile
          mrow[r] = mn;
          lrow[r] *= corr;
#pragma unroll
          for (int d = 0; d < 8; d++) oacc[d][r] *= corr;
        }
      }
      float rsum[4] = {0.f, 0.f, 0.f, 0.f};
#pragma unroll
      for (int ck = 0; ck < 4; ck++)
#pragma unroll
        for (int r = 0; r < 4; r++) {
          const float p = __expf(sacc[ck][r] - mrow[r]);  // masked -> 0
          rsum[r] += p;
          const int prow = (lane >> 4) * 4 + r;
          const int pcol = ck * 16 + (lane & 15);
          *(unsigned short*)((char*)Ps[w] +
                             ((prow * 128 + pcol * 2) ^ ((prow & 7) << 4))) =
              f2bf(p);
        }
#pragma unroll
      for (int off = 1; off < 16; off <<= 1)
#pragma unroll
        for (int r = 0; r < 4; r++) rsum[r] += __shfl_xor(rsum[r], off, 64);
#pragma unroll
      for (int r = 0; r < 4; r++) lrow[r] += rsum[r];

      // O += P V : A = P [16 q][64 k], B = V [64 k][128 d] (from V^T tile)
      bf16x8 pf[2];
      {
        const int prow = lane & 15;
#pragma unroll
        for (int kk = 0; kk < 2; kk++) {
          const int chunk = kk * 4 + (lane >> 4);
          pf[kk] = *(const bf16x8*)((const char*)Ps[w] + prow * 128 +
                                    ((chunk ^ (prow & 7)) << 4));
        }
      }
      __builtin_amdgcn_s_setprio(1);
#pragma unroll
      for (int d = 0; d < 8; ++d) {
        const int vrow = d * 16 + (lane & 15);
#pragma unroll
        for (int kk = 0; kk < 2; ++kk) {
          const int chunk = kk * 4 + (lane >> 4);
          const bf16x8 vf = *(const bf16x8*)((const char*)Vc + vrow * 128 +
                                             ((chunk ^ (vrow & 7)) << 4));
          oacc[d] = __builtin_amdgcn_mfma_f32_16x16x32_bf16(pf[kk], vf, oacc[d],
                                                            0, 0, 0);
        }
      }
      __builtin_amdgcn_s_setprio(0);

      __syncthreads();  // prefetch drained here; buffers swap
      cur ^= 1;
    }

    // epilogue: ctx[b][s][h*128 + d]
#pragma unroll
    for (int r = 0; r < 4; r++) {
      const float inv = 1.f / lrow[r];
      const int srow = q0 + (lane >> 4) * 4 + r;
      unsigned short* dst =
          ctx + (b_ * S_LEN + srow) * DMODEL + h * HDIM + (lane & 15);
#pragma unroll
      for (int d = 0; d < 8; d++) dst[d * 16] = f2bf(oacc[d][r] * inv);
    }
  }
}

// ---------------- output projection GEMM ----------------
__global__ __launch_bounds__(256, 2) void gemm_out(
    const unsigned short* __restrict__ A,  // ctx [4096][2048] bf16
    const unsigned short* __restrict__ W,  // o_w [2048][2048] bf16
    const float* __restrict__ bias, float* __restrict__ out) {
  __shared__ unsigned short As[128 * 32];
  __shared__ unsigned short Bs[128 * 32];
  const int t = threadIdx.x;
  const int lane = t & 63;
  const int w = t >> 6;
  const int m0 = blockIdx.x * 128;
  const int n0 = blockIdx.y * 128;
  const int wr = w >> 1, wc = w & 1;

  f32x4 acc[4][4];
#pragma unroll
  for (int i = 0; i < 4; i++)
#pragma unroll
    for (int j = 0; j < 4; j++)
#pragma unroll
      for (int e = 0; e < 4; e++) acc[i][j][e] = 0.f;

  const int r0 = t >> 2;
  const int kc0 = (t & 3) * 8;
  const unsigned short* Arow0 = A + (m0 + r0) * DMODEL + kc0;
  const unsigned short* Arow1 = A + (m0 + 64 + r0) * DMODEL + kc0;
  const unsigned short* Wrow0 = W + (n0 + r0) * DMODEL + kc0;
  const unsigned short* Wrow1 = W + (n0 + 64 + r0) * DMODEL + kc0;
  char* AsB = (char*)As;
  char* BsB = (char*)Bs;
  const int frow = lane & 15;
  const int fcol = (lane >> 4) * 8;

  for (int k0 = 0; k0 < DMODEL; k0 += 32) {
    __syncthreads();
    gload16(Arow0 + k0, AsB + w * 1024);
    gload16(Arow1 + k0, AsB + 4096 + w * 1024);
    gload16(Wrow0 + k0, BsB + w * 1024);
    gload16(Wrow1 + k0, BsB + 4096 + w * 1024);
    __syncthreads();
    bf16x8 af[4], bfr[4];
#pragma unroll
    for (int i = 0; i < 4; i++)
      af[i] = *(const bf16x8*)&As[(wr * 64 + i * 16 + frow) * 32 + fcol];
#pragma unroll
    for (int j = 0; j < 4; j++)
      bfr[j] = *(const bf16x8*)&Bs[(wc * 64 + j * 16 + frow) * 32 + fcol];
#pragma unroll
    for (int i = 0; i < 4; i++)
#pragma unroll
      for (int j = 0; j < 4; j++)
        acc[i][j] = __builtin_amdgcn_mfma_f32_16x16x32_bf16(af[i], bfr[j],
                                                            acc[i][j], 0, 0, 0);
  }

#pragma unroll
  for (int j = 0; j < 4; j++) {
    const int n = n0 + wc * 64 + j * 16 + (lane & 15);
    const float bv = bias[n];
#pragma unroll
    for (int i = 0; i < 4; i++) {
      const int mrow = m0 + wr * 64 + i * 16 + (lane >> 4) * 4;
      float* dst = out + mrow * DMODEL + n;
#pragma unroll
      for (int r = 0; r < 4; r++) dst[r * DMODEL] = acc[i][j][r] + bv;
    }
  }
}

// ---------------- host launcher ----------------
extern "C" void kernel_launch(void* const* d_in, const int* in_sizes, int n_in,
                              void* d_out, int out_size, void* d_ws,
                              size_t ws_size, hipStream_t stream) {
  const float* x  = (const float*)d_in[0];
  const float* qw = (const float*)d_in[1];
  const float* qb = (const float*)d_in[2];
  const float* kw = (const float*)d_in[3];
  const float* kb = (const float*)d_in[4];
  const float* vw = (const float*)d_in[5];
  const float* vb = (const float*)d_in[6];
  const float* ow = (const float*)d_in[7];
  const float* ob = (const float*)d_in[8];
  float* out = (float*)d_out;

  // workspace layout (bf16 elements); total 117,440,512 bytes
  unsigned short* xb   = (unsigned short*)d_ws;        // x      [4096][2048]
  unsigned short* wqkv = xb + (size_t)8388608;         // [6144][2048]
  unsigned short* wo   = wqkv + (size_t)12582912;      // [2048][2048]
  unsigned short* qt_  = wo + (size_t)4194304;         // Q  [B,H,S,HD]
  unsigned short* kt_  = qt_ + (size_t)8388608;        // K  [B,H,S,HD]
  unsigned short* vt_  = kt_ + (size_t)8388608;        // V^T[B,H,HD,S]
  unsigned short* ctx  = vt_ + (size_t)8388608;        // ctx[B,S,D]

  cvt_f32_bf16<<<8192, 256, 0, stream>>>(x, xb, 2097152);
  cvt_f32_bf16<<<4096, 256, 0, stream>>>(qw, wqkv, 1048576);
  cvt_f32_bf16<<<4096, 256, 0, stream>>>(kw, wqkv + 4194304, 1048576);
  cvt_f32_bf16<<<4096, 256, 0, stream>>>(vw, wqkv + 8388608, 1048576);
  cvt_f32_bf16<<<4096, 256, 0, stream>>>(ow, wo, 1048576);

  gemm_qkv<<<dim3(32, 48), 256, 0, stream>>>(xb, wqkv, qb, kb, vb, qt_, kt_, vt_);
  attn_fwd<<<dim3(16, 32), 256, 0, stream>>>(qt_, kt_, vt_, ctx);
  gemm_out<<<dim3(32, 16), 256, 0, stream>>>(ctx, wo, ob, out);
}